// Round 18
// baseline (218.280 us; speedup 1.0000x reference)
//
#include <hip/hip_runtime.h>
#include <hip/hip_bf16.h>

typedef unsigned short u16;
typedef unsigned int u32;
typedef __bf16 bf16_t;
typedef bf16_t bf16x8 __attribute__((ext_vector_type(8)));
typedef float f32x4 __attribute__((ext_vector_type(4)));
typedef u16 u16x4 __attribute__((ext_vector_type(4)));
typedef u16 u16x8 __attribute__((ext_vector_type(8)));
typedef u32 u32x2 __attribute__((ext_vector_type(2)));
typedef u32 u32x4 __attribute__((ext_vector_type(4)));
typedef int intx2 __attribute__((ext_vector_type(2)));

#define MFMA16(a, b, c) __builtin_amdgcn_mfma_f32_16x16x32_bf16((a), (b), (c), 0, 0, 0)

// softmax scale folded into Q: 1/sqrt(64) * log2(e)
#define QSCL 0.18033688011112042f

__device__ __forceinline__ u16 f2b(float f) {
  bf16_t h = (bf16_t)f;
  return __builtin_bit_cast(u16, h);
}

__device__ __forceinline__ void gload_lds16(const void* src, void* dst) {
  __builtin_amdgcn_global_load_lds(
      (const __attribute__((address_space(1))) void*)src,
      (__attribute__((address_space(3))) void*)dst, 16, 0, 0);
}

// Read one 16B MFMA fragment from a swizzled LDS tile with 64-bf16 (128B) rows.
// Swizzle: 16B chunk c of row r is stored at chunk c ^ (r & 7).
__device__ __forceinline__ bf16x8 frag_read(const u16* tile, int row, int kchunk) {
  int off = row * 128 + ((kchunk ^ (row & 7)) << 4);
  return *reinterpret_cast<const bf16x8*>(reinterpret_cast<const char*>(tile) + off);
}

// Stage a 128-row x 64-bf16 tile (16KB) global->LDS, pre-swizzled global source
// so LDS dest stays linear (base + lane*16). 4 waves x 4 instrs, 8 rows each.
__device__ __forceinline__ void stage128(const u16* g, int rowStrideElts, u16* tile, int tid) {
  int lane = tid & 63, w = tid >> 6;
#pragma unroll
  for (int i = 0; i < 4; ++i) {
    int r = w * 32 + i * 8 + (lane >> 3);
    int cs = (lane & 7) ^ (r & 7);
    gload_lds16(g + (size_t)r * rowStrideElts + cs * 8, tile + r * 64 + (lane & 7) * 8);
  }
}

// ---------- convert / transpose ----------
__global__ __launch_bounds__(256) void cvt_f32_bf16(const float* __restrict__ in,
                                                    u16* __restrict__ out, int n4) {
  int i = blockIdx.x * 256 + threadIdx.x;
  if (i < n4) {
    float4 f = reinterpret_cast<const float4*>(in)[i];
    u16x4 o;
    o[0] = f2b(f.x); o[1] = f2b(f.y); o[2] = f2b(f.z); o[3] = f2b(f.w);
    __builtin_nontemporal_store(o, reinterpret_cast<u16x4*>(out) + i);
  }
}

// Fused weight transposes: z=0 -> w_attn (N=3072, 96 col-blocks),
// z=1 -> w_proj (N=1024, 32 col-blocks). in[1024][N] f32 -> out[N][1024] bf16.
// Whole-block early return happens BEFORE any barrier (safe).
__global__ __launch_bounds__(256) void transpose_cvt2(const float* __restrict__ inA,
                                                      u16* __restrict__ outA,
                                                      const float* __restrict__ inB,
                                                      u16* __restrict__ outB) {
  const float* in;
  u16* out;
  int N;
  if (blockIdx.z == 0) {
    in = inA; out = outA; N = 3072;
  } else {
    if (blockIdx.x >= 32) return;  // w_proj: only 32 col-blocks of the 96
    in = inB; out = outB; N = 1024;
  }
  __shared__ float t[32][33];
  int n0 = blockIdx.x * 32, k0 = blockIdx.y * 32;
  int tx = threadIdx.x & 31, ty = threadIdx.x >> 5;  // ty in 0..7
#pragma unroll
  for (int i = 0; i < 32; i += 8)
    t[ty + i][tx] = in[(size_t)(k0 + ty + i) * N + n0 + tx];
  __syncthreads();
#pragma unroll
  for (int i = 0; i < 32; i += 8)
    __builtin_nontemporal_store(f2b(t[tx][ty + i]),
                                out + (size_t)(n0 + ty + i) * 1024 + k0 + tx);
}

// ---------- GEMM1: qkv = x @ w_attn + b_attn, routed to q/k/vt ----------
// Q is pre-scaled by QSCL so attention scores exit MFMA in log2-domain.
// L2-blocked XCD mapping: each XCD owns bm-chunk [8x..8x+7] (A-chunk 2MB,
// stays L2-resident) and sweeps all bn with bm fastest.
// All outputs nontemporal (never re-read on the writing XCD): keeps the
// A-chunk resident instead of being evicted by write-allocate traffic.
// vt epilogue: per-wave LDS transpose -> coalesced 16B stores.
__global__ __launch_bounds__(256) void gemm_qkv(const u16* __restrict__ xb,
                                                const u16* __restrict__ waT,
                                                const float* __restrict__ bias,
                                                u16* __restrict__ q, u16* __restrict__ kk,
                                                u16* __restrict__ vt) {
  __shared__ u16 ldsU[2][128 * 64];
  u16* lA = ldsU[0];
  u16* lB = ldsU[1];
  int tid = threadIdx.x, lane = tid & 63, w = tid >> 6;
  int wr = w >> 1, wc = w & 1;
  int orig = blockIdx.x + gridDim.x * blockIdx.y;
  int xcd = orig & 7, local = orig >> 3;      // 1536 blocks: 8 XCDs x 192
  int bm = xcd * 8 + (local & 7);             // bm-chunk per XCD
  int bn = local >> 3;                        // 0..23, swept slowly
  f32x4 acc[4][4] = {};
  const u16* gA = xb + (size_t)bm * 128 * 1024;
  const u16* gB = waT + (size_t)bn * 128 * 1024;
  for (int k0 = 0; k0 < 1024; k0 += 64) {
    stage128(gA + k0, 1024, lA, tid);
    stage128(gB + k0, 1024, lB, tid);
    __syncthreads();
#pragma unroll
    for (int s = 0; s < 2; ++s) {
      bf16x8 af[4], bfr[4];
#pragma unroll
      for (int mi = 0; mi < 4; ++mi)
        af[mi] = frag_read(lA, wr * 64 + mi * 16 + (lane & 15), (lane >> 4) + s * 4);
#pragma unroll
      for (int ni = 0; ni < 4; ++ni)
        bfr[ni] = frag_read(lB, wc * 64 + ni * 16 + (lane & 15), (lane >> 4) + s * 4);
#pragma unroll
      for (int mi = 0; mi < 4; ++mi)
#pragma unroll
        for (int ni = 0; ni < 4; ++ni)
          acc[mi][ni] = MFMA16(af[mi], bfr[ni], acc[mi][ni]);
    }
    __syncthreads();
  }
  int m0 = bm * 128 + wr * 64;
  int n0 = bn * 128 + wc * 64;
  if (bn >= 16) {
    // ---- V^T part: transpose in per-wave LDS, store coalesced 16B ----
    int ln = lane & 15, g = lane >> 4;
    int hB = (n0 - 2048) >> 6;          // head, uniform per wave
    u16* scr = ldsU[0] + w * 4096;      // 8KB per wave
#pragma unroll
    for (int ni = 0; ni < 4; ++ni) {
      int d = ni * 16 + ln;
      float bv = bias[n0 + ni * 16 + ln];
#pragma unroll
      for (int mi = 0; mi < 4; ++mi) {
        u16x4 v4;
#pragma unroll
        for (int j = 0; j < 4; ++j) v4[j] = f2b(acc[mi][ni][j] + bv);
        int c = (mi * 4 + g) ^ (d & 15);  // chunk swizzle
        *reinterpret_cast<u16x4*>(reinterpret_cast<char*>(scr) + d * 128 + c * 8) = v4;
      }
    }
    asm volatile("s_waitcnt lgkmcnt(0)" ::: "memory");
    __builtin_amdgcn_sched_barrier(0);
    __builtin_amdgcn_wave_barrier();
    int bb = bm >> 4;
    int t0 = (bm & 15) * 128 + wr * 64 + (lane & 7) * 8;
#pragma unroll
    for (int p = 0; p < 8; ++p) {
      int dr = p * 8 + (lane >> 3);
      int c0 = (lane & 7) * 2;
      u16x4 lo = *reinterpret_cast<const u16x4*>(
          reinterpret_cast<const char*>(scr) + dr * 128 + ((c0 ^ (dr & 15)) * 8));
      u16x4 hi = *reinterpret_cast<const u16x4*>(
          reinterpret_cast<const char*>(scr) + dr * 128 + (((c0 + 1) ^ (dr & 15)) * 8));
      u16x8 o8;
      o8[0] = lo[0]; o8[1] = lo[1]; o8[2] = lo[2]; o8[3] = lo[3];
      o8[4] = hi[0]; o8[5] = hi[1]; o8[6] = hi[2]; o8[7] = hi[3];
      __builtin_nontemporal_store(
          o8, reinterpret_cast<u16x8*>(vt + ((size_t)(bb * 16 + hB) * 64 + dr) * 2048 + t0));
    }
  } else {
    // ---- q/k parts: 16-lane-contiguous u16 stores (32B groups) ----
#pragma unroll
    for (int ni = 0; ni < 4; ++ni) {
      int col = n0 + ni * 16 + (lane & 15);
      float bv = bias[col];
      int part = col >> 10;
      int cin = col & 1023;
      int h = cin >> 6, d = cin & 63;
      float fct = (part == 0) ? QSCL : 1.0f;
#pragma unroll
      for (int mi = 0; mi < 4; ++mi) {
#pragma unroll
        for (int j = 0; j < 4; ++j) {
          int row = m0 + mi * 16 + (lane >> 4) * 4 + j;
          int b = row >> 11, t = row & 2047;
          u16 hv = f2b((acc[mi][ni][j] + bv) * fct);
          if (part == 0)
            __builtin_nontemporal_store(hv, q + (((size_t)(b * 16 + h) * 2048 + t) << 6) + d);
          else
            __builtin_nontemporal_store(hv, kk + (((size_t)(b * 16 + h) * 2048 + t) << 6) + d);
        }
      }
    }
  }
}

// ---------- GEMM2: out = att @ w_proj + b_proj (f32 out) ----------
// Same L2-blocked XCD mapping: bm-chunk per XCD, bn swept slowly.
// Output stores nontemporal (write-only result).
__global__ __launch_bounds__(256) void gemm_proj(const u16* __restrict__ att,
                                                 const u16* __restrict__ wpT,
                                                 const float* __restrict__ bias,
                                                 float* __restrict__ out) {
  __shared__ u16 lA[128 * 64];
  __shared__ u16 lB[128 * 64];
  int tid = threadIdx.x, lane = tid & 63, w = tid >> 6;
  int wr = w >> 1, wc = w & 1;
  int orig = blockIdx.x + gridDim.x * blockIdx.y;
  int xcd = orig & 7, local = orig >> 3;      // 512 blocks: 8 XCDs x 64
  int bm = xcd * 8 + (local & 7);             // bm-chunk per XCD
  int bn = local >> 3;                        // 0..7
  f32x4 acc[4][4] = {};
  const u16* gA = att + (size_t)bm * 128 * 1024;
  const u16* gB = wpT + (size_t)bn * 128 * 1024;
  for (int k0 = 0; k0 < 1024; k0 += 64) {
    stage128(gA + k0, 1024, lA, tid);
    stage128(gB + k0, 1024, lB, tid);
    __syncthreads();
#pragma unroll
    for (int s = 0; s < 2; ++s) {
      bf16x8 af[4], bfr[4];
#pragma unroll
      for (int mi = 0; mi < 4; ++mi)
        af[mi] = frag_read(lA, wr * 64 + mi * 16 + (lane & 15), (lane >> 4) + s * 4);
#pragma unroll
      for (int ni = 0; ni < 4; ++ni)
        bfr[ni] = frag_read(lB, wc * 64 + ni * 16 + (lane & 15), (lane >> 4) + s * 4);
#pragma unroll
      for (int mi = 0; mi < 4; ++mi)
#pragma unroll
        for (int ni = 0; ni < 4; ++ni)
          acc[mi][ni] = MFMA16(af[mi], bfr[ni], acc[mi][ni]);
    }
    __syncthreads();
  }
  int m0 = bm * 128 + wr * 64;
  int n0 = bn * 128 + wc * 64;
#pragma unroll
  for (int ni = 0; ni < 4; ++ni) {
    int col = n0 + ni * 16 + (lane & 15);
    float bv = bias[col];
#pragma unroll
    for (int mi = 0; mi < 4; ++mi)
#pragma unroll
      for (int j = 0; j < 4; ++j) {
        int row = m0 + mi * 16 + (lane >> 4) * 4 + j;
        __builtin_nontemporal_store(acc[mi][ni][j] + bv, out + (size_t)row * 1024 + col);
      }
  }
}

// ---------- flash attention (byte-identical to R16: proven 87.0us) ----------
// Swapped-operand S^T = mfma(K,Q), in-register P redistribution, K+V
// triple-buffered counted-vmcnt(4) pipeline. Zero-tail load balance:
//   g=0..9 : (31-g, 11+g); g=10: (21,10),(9,0); g=11: (8,1),(7,2),(6,3),(5,4)
// Grid 64x12 = 768 blocks = exactly 3/CU -> all co-resident, no tail round.
// (R11-R13: 1-deep S-pipelining spills to scratch here -- axis closed.)

__device__ __forceinline__ void stage_kv(const u16* kb, const u16* vb, int kt,
                                         u16* lK, u16* lV, int tid) {
  int lane = tid & 63, w = tid >> 6;
#pragma unroll
  for (int i = 0; i < 2; ++i) {
    int r = w * 16 + i * 8 + (lane >> 3);
    int cs = (lane & 7) ^ (r & 7);
    gload_lds16(kb + (size_t)(kt * 64 + r) * 64 + cs * 8, lK + r * 64 + (lane & 7) * 8);
    gload_lds16(vb + (size_t)r * 2048 + kt * 64 + cs * 8, lV + r * 64 + (lane & 7) * 8);
  }
}

// Redistribute two kc-pairs of packed P dwords into one B-fragment.
__device__ __forceinline__ bf16x8 pdist(u32 a0, u32 a1, u32 b0, u32 b1, bool odd) {
  intx2 r0 = __builtin_amdgcn_permlane32_swap((int)a0, (int)b0, false, false);
  intx2 r1 = __builtin_amdgcn_permlane32_swap((int)a1, (int)b1, false, false);
  u32 x0 = __shfl_xor((u32)r0[1], 16, 64);
  u32 x1 = __shfl_xor((u32)r1[1], 16, 64);
  u32 y0 = __shfl_xor((u32)r0[0], 16, 64);
  u32 y1 = __shfl_xor((u32)r1[0], 16, 64);
  u32x4 f;
  f[0] = odd ? x0 : (u32)r0[0];
  f[1] = odd ? x1 : (u32)r1[0];
  f[2] = odd ? (u32)r0[1] : y0;
  f[3] = odd ? (u32)r1[1] : y1;
  return __builtin_bit_cast(bf16x8, f);
}

__global__ __launch_bounds__(256, 3) void attn_fwd(const u16* __restrict__ q,
                                                   const u16* __restrict__ kk,
                                                   const u16* __restrict__ vt,
                                                   u16* __restrict__ att) {
  __shared__ u16 lK[3][64 * 64];
  __shared__ u16 lV[3][64 * 64];
  int tid = threadIdx.x, lane = tid & 63, w = tid >> 6;
  int ln = lane & 15, g = lane >> 4;
  int gh = g >> 1, gl = g & 1;
  bool godd = (g & 1) != 0;
  int bh = blockIdx.x;
  int grp = blockIdx.y;   // 0..11
  const u16* qb = q + (size_t)bh * 2048 * 64;
  const u16* kb = kk + (size_t)bh * 2048 * 64;
  const u16* vb = vt + (size_t)bh * 64 * 2048;
  int b = bh >> 4, h = bh & 15;

  // softmax for one state; emits the two P^T B-fragments in registers
  auto softmax_state = [&](f32x4* sf, float& m_r, float& l_r, f32x4* o,
                           bool domask, int k0, int qg,
                           bf16x8& pf0, bf16x8& pf1) {
    if (domask) {
#pragma unroll
      for (int kc = 0; kc < 4; ++kc)
#pragma unroll
        for (int j = 0; j < 4; ++j)
          if (k0 + kc * 16 + g * 4 + j > qg) sf[kc][j] = -1e30f;
    }
    f32x4 m4;
#pragma unroll
    for (int j = 0; j < 4; ++j)
      m4[j] = fmaxf(fmaxf(sf[0][j], sf[1][j]), fmaxf(sf[2][j], sf[3][j]));
    float mxl = fmaxf(fmaxf(m4[0], m4[1]), fmaxf(m4[2], m4[3]));
    if (!__all(mxl - m_r <= 8.f)) {  // defer-max: rescale only on big growth
      float mx = fmaxf(mxl, __shfl_xor(mxl, 16, 64));
      mx = fmaxf(mx, __shfl_xor(mx, 32, 64));
      mx = fmaxf(m_r, mx);
      float sc = __builtin_amdgcn_exp2f(m_r - mx);
      m_r = mx;
      l_r *= sc;
#pragma unroll
      for (int dc = 0; dc < 4; ++dc) o[dc] *= sc;
    }
    u32 d0[4], d1[4];
    float rsk[4];
#pragma unroll
    for (int kc = 0; kc < 4; ++kc) {
      u16x4 v4;
      float p0 = __builtin_amdgcn_exp2f(sf[kc][0] - m_r);
      float p1 = __builtin_amdgcn_exp2f(sf[kc][1] - m_r);
      float p2 = __builtin_amdgcn_exp2f(sf[kc][2] - m_r);
      float p3 = __builtin_amdgcn_exp2f(sf[kc][3] - m_r);
      v4[0] = f2b(p0); v4[1] = f2b(p1); v4[2] = f2b(p2); v4[3] = f2b(p3);
      rsk[kc] = (p0 + p1) + (p2 + p3);  // tree sum (iteration-local, no spill)
      u32x2 dd = __builtin_bit_cast(u32x2, v4);
      d0[kc] = dd[0];
      d1[kc] = dd[1];
    }
    l_r += (rsk[0] + rsk[1]) + (rsk[2] + rsk[3]);
    pf0 = pdist(d0[0], d1[0], d0[1], d1[1], godd);
    pf1 = pdist(d0[2], d1[2], d0[3], d1[3], godd);
  };

  // O^T -> O transpose via per-wave lK[0] scratch, coalesced 16B stores
  u16* lPw = &lK[0][0] + w * 1024;
  int prow = ln * 128;
  int xorq = (ln & 7) << 4;
  auto epi = [&](const f32x4* o, float l_r, int q0w) {
    float lt = l_r + __shfl_xor(l_r, 16, 64);
    lt += __shfl_xor(lt, 32, 64);
    float inv = __builtin_amdgcn_rcpf(lt);
#pragma unroll
    for (int dc = 0; dc < 4; ++dc) {
      u16x4 v4;
#pragma unroll
      for (int j = 0; j < 4; ++j) v4[j] = f2b(o[dc][j] * inv);
      *reinterpret_cast<u16x4*>(reinterpret_cast<char*>(lPw) + prow +
                                ((((dc << 1) + gh) << 4) ^ xorq) + gl * 8) = v4;
    }
    asm volatile("s_waitcnt lgkmcnt(0)" ::: "memory");
    __builtin_amdgcn_sched_barrier(0);
    __builtin_amdgcn_wave_barrier();
    bf16x8 r0 = frag_read(lPw, ln, g);
    bf16x8 r1 = frag_read(lPw, ln, g + 4);
    __builtin_amdgcn_sched_barrier(0);
    int t = q0w + ln;
    u16* dst = att + (size_t)(b * 2048 + t) * 1024 + h * 64;
    *reinterpret_cast<bf16x8*>(dst + g * 8) = r0;
    *reinterpret_cast<bf16x8*>(dst + 32 + g * 8) = r1;
  };

  int njobs = (grp < 10) ? 1 : ((grp == 10) ? 2 : 4);

  for (int jj = 0; jj < njobs; ++jj) {
    int qtB, qtA;  // uniform scalars per job
    if (grp < 10) {
      qtB = 31 - grp; qtA = 11 + grp;
    } else if (grp == 10) {
      qtB = jj ? 9 : 21; qtA = jj ? 0 : 10;
    } else {
      qtB = 8 - jj; qtA = 1 + jj;
    }
    int q0A = qtA * 64 + w * 16;
    int q0B = qtB * 64 + w * 16;

    bf16x8 aqA[2], aqB[2];
    {
      const u16* pa = qb + (size_t)(q0A + ln) * 64 + g * 8;
      const u16* pb = qb + (size_t)(q0B + ln) * 64 + g * 8;
      aqA[0] = *reinterpret_cast<const bf16x8*>(pa);
      aqA[1] = *reinterpret_cast<const bf16x8*>(pa + 32);
      aqB[0] = *reinterpret_cast<const bf16x8*>(pb);
      aqB[1] = *reinterpret_cast<const bf16x8*>(pb + 32);
    }

    float mA = -1e30f, lAx = 0.f, mB = -1e30f, lBx = 0.f;
    f32x4 oA[4] = {}, oB[4] = {};

    // prologue: two tiles in flight before the loop (qtB >= 1 for all jobs)
    stage_kv(kb, vb, 0, &lK[0][0], &lV[0][0], tid);
    if (qtB >= 1) stage_kv(kb, vb, 1, &lK[1][0], &lV[1][0], tid);

    for (int kt = 0; kt <= qtB; ++kt) {
      // wait for tile kt (leave tile kt+1's 4 loads in flight), then sync
      if (kt < qtB) {
        asm volatile("s_waitcnt vmcnt(4)" ::: "memory");
      } else {
        asm volatile("s_waitcnt vmcnt(0)" ::: "memory");
      }
      __builtin_amdgcn_s_barrier();
      // prefetch tile kt+2 into the buffer last read at compute(kt-1)
      if (kt + 2 <= qtB)
        stage_kv(kb, vb, kt + 2, &lK[(kt + 2) % 3][0], &lV[(kt + 2) % 3][0], tid);
      int cur = kt % 3;
      const u16* Kt = &lK[cur][0];
      const u16* Vt = &lV[cur][0];
      bool doA = (kt <= qtA);

      // QK^T both states, K-fragments shared
      f32x4 sB[4], sA[4];
      __builtin_amdgcn_s_setprio(1);
#pragma unroll
      for (int kc = 0; kc < 4; ++kc) {
        f32x4 zB = {}, zA = {};
#pragma unroll
        for (int s = 0; s < 2; ++s) {
          bf16x8 kf = frag_read(Kt, kc * 16 + ln, g + 4 * s);
          zB = MFMA16(kf, aqB[s], zB);
          if (doA) zA = MFMA16(kf, aqA[s], zA);
        }
        sB[kc] = zB;
        sA[kc] = zA;
      }
      __builtin_amdgcn_s_setprio(0);

      // V-fragment register cache (shared by both states; loads overlap SM_B)
      bf16x8 vf0[4], vf1[4];
#pragma unroll
      for (int dc = 0; dc < 4; ++dc) {
        vf0[dc] = frag_read(Vt, dc * 16 + ln, g);
        vf1[dc] = frag_read(Vt, dc * 16 + ln, g + 4);
      }

      bf16x8 pB0, pB1, pA0, pA1;
      softmax_state(sB, mB, lBx, oB, kt == qtB, kt * 64, q0B + ln, pB0, pB1);
      __builtin_amdgcn_s_setprio(1);
#pragma unroll
      for (int dc = 0; dc < 4; ++dc) {
        oB[dc] = MFMA16(vf0[dc], pB0, oB[dc]);
        oB[dc] = MFMA16(vf1[dc], pB1, oB[dc]);
      }
      __builtin_amdgcn_s_setprio(0);
      if (doA) {
        // SM_A's VALU chain overlaps PV_B's MFMAs (independent)
        softmax_state(sA, mA, lAx, oA, kt == qtA, kt * 64, q0A + ln, pA0, pA1);
        __builtin_amdgcn_s_setprio(1);
#pragma unroll
        for (int dc = 0; dc < 4; ++dc) {
          oA[dc] = MFMA16(vf0[dc], pA0, oA[dc]);
          oA[dc] = MFMA16(vf1[dc], pA1, oA[dc]);
        }
        __builtin_amdgcn_s_setprio(0);
      }
    }

    // epilogue: reduce l; transpose O^T -> O via lK[0] scratch
    __syncthreads();  // everyone done with K/V LDS for this job
    epi(oB, lBx, q0B);
    epi(oA, lAx, q0A);
    __syncthreads();  // scratch reads done before next job's staging
  }
}

extern "C" void kernel_launch(void* const* d_in, const int* in_sizes, int n_in,
                              void* d_out, int out_size, void* d_ws, size_t ws_size,
                              hipStream_t stream) {
  const float* x = (const float*)d_in[0];
  const float* w_attn = (const float*)d_in[1];
  const float* b_attn = (const float*)d_in[2];
  const float* w_proj = (const float*)d_in[3];
  const float* b_proj = (const float*)d_in[4];
  float* out = (float*)d_out;

  // workspace (u16 units): xb 8.39M (aliased by att after gemm_qkv),
  // waT 3.15M, wpT 1.05M, vt 8.39M  => ~42 MB total
  u16* ws = (u16*)d_ws;
  u16* xb = ws;
  u16* waT = xb + 8388608;
  u16* wpT = waT + 3145728;
  u16* vtx = wpT + 1048576;
  u16* att = xb;  // alias: xb dead after gemm_qkv
  // q/k live in d_out (33.5MB) as scratch; overwritten by gemm_proj at the end
  u16* qx = (u16*)d_out;
  u16* kx = qx + 8388608;

  cvt_f32_bf16<<<8192, 256, 0, stream>>>(x, xb, 2097152);
  transpose_cvt2<<<dim3(96, 32, 2), 256, 0, stream>>>(w_attn, waT, w_proj, wpT);
  gemm_qkv<<<dim3(64, 24), 256, 0, stream>>>(xb, waT, b_attn, qx, kx, vtx);
  attn_fwd<<<dim3(64, 12), 256, 0, stream>>>(qx, kx, vtx, att);
  gemm_proj<<<dim3(64, 8), 256, 0, stream>>>(att, wpT, b_proj, out);
}

// Round 19
// 184.617 us; speedup vs baseline: 1.1823x; 1.1823x over previous
//
#include <hip/hip_runtime.h>
#include <hip/hip_bf16.h>

typedef unsigned short u16;
typedef unsigned int u32;
typedef __bf16 bf16_t;
typedef bf16_t bf16x8 __attribute__((ext_vector_type(8)));
typedef float f32x4 __attribute__((ext_vector_type(4)));
typedef u16 u16x4 __attribute__((ext_vector_type(4)));
typedef u16 u16x8 __attribute__((ext_vector_type(8)));
typedef u32 u32x2 __attribute__((ext_vector_type(2)));
typedef u32 u32x4 __attribute__((ext_vector_type(4)));
typedef int intx2 __attribute__((ext_vector_type(2)));

#define MFMA16(a, b, c) __builtin_amdgcn_mfma_f32_16x16x32_bf16((a), (b), (c), 0, 0, 0)

// softmax scale folded into Q: 1/sqrt(64) * log2(e)
#define QSCL 0.18033688011112042f

__device__ __forceinline__ u16 f2b(float f) {
  bf16_t h = (bf16_t)f;
  return __builtin_bit_cast(u16, h);
}

__device__ __forceinline__ void gload_lds16(const void* src, void* dst) {
  __builtin_amdgcn_global_load_lds(
      (const __attribute__((address_space(1))) void*)src,
      (__attribute__((address_space(3))) void*)dst, 16, 0, 0);
}

// Read one 16B MFMA fragment from a swizzled LDS tile with 64-bf16 (128B) rows.
// Swizzle: 16B chunk c of row r is stored at chunk c ^ (r & 7).
__device__ __forceinline__ bf16x8 frag_read(const u16* tile, int row, int kchunk) {
  int off = row * 128 + ((kchunk ^ (row & 7)) << 4);
  return *reinterpret_cast<const bf16x8*>(reinterpret_cast<const char*>(tile) + off);
}

// Stage a 128-row x 64-bf16 tile (16KB) global->LDS, pre-swizzled global source
// so LDS dest stays linear (base + lane*16). 4 waves x 4 instrs, 8 rows each.
__device__ __forceinline__ void stage128(const u16* g, int rowStrideElts, u16* tile, int tid) {
  int lane = tid & 63, w = tid >> 6;
#pragma unroll
  for (int i = 0; i < 4; ++i) {
    int r = w * 32 + i * 8 + (lane >> 3);
    int cs = (lane & 7) ^ (r & 7);
    gload_lds16(g + (size_t)r * rowStrideElts + cs * 8, tile + r * 64 + (lane & 7) * 8);
  }
}

// ---------- convert / transpose ----------
__global__ __launch_bounds__(256) void cvt_f32_bf16(const float* __restrict__ in,
                                                    u16* __restrict__ out, int n4) {
  int i = blockIdx.x * 256 + threadIdx.x;
  if (i < n4) {
    float4 f = reinterpret_cast<const float4*>(in)[i];
    ushort4 o;
    o.x = f2b(f.x); o.y = f2b(f.y); o.z = f2b(f.z); o.w = f2b(f.w);
    reinterpret_cast<ushort4*>(out)[i] = o;
  }
}

// Fused weight transposes: z=0 -> w_attn (N=3072, 96 col-blocks),
// z=1 -> w_proj (N=1024, 32 col-blocks). in[1024][N] f32 -> out[N][1024] bf16.
// Whole-block early return happens BEFORE any barrier (safe).
__global__ __launch_bounds__(256) void transpose_cvt2(const float* __restrict__ inA,
                                                      u16* __restrict__ outA,
                                                      const float* __restrict__ inB,
                                                      u16* __restrict__ outB) {
  const float* in;
  u16* out;
  int N;
  if (blockIdx.z == 0) {
    in = inA; out = outA; N = 3072;
  } else {
    if (blockIdx.x >= 32) return;  // w_proj: only 32 col-blocks of the 96
    in = inB; out = outB; N = 1024;
  }
  __shared__ float t[32][33];
  int n0 = blockIdx.x * 32, k0 = blockIdx.y * 32;
  int tx = threadIdx.x & 31, ty = threadIdx.x >> 5;  // ty in 0..7
#pragma unroll
  for (int i = 0; i < 32; i += 8)
    t[ty + i][tx] = in[(size_t)(k0 + ty + i) * N + n0 + tx];
  __syncthreads();
#pragma unroll
  for (int i = 0; i < 32; i += 8)
    out[(size_t)(n0 + ty + i) * 1024 + k0 + tx] = f2b(t[tx][ty + i]);
}

// ---------- GEMM1: qkv = x @ w_attn + b_attn, routed to q/k/vt ----------
// Q is pre-scaled by QSCL so attention scores exit MFMA in log2-domain.
// L2-blocked XCD mapping: each XCD owns bm-chunk [8x..8x+7] (A-chunk 2MB,
// stays L2-resident) and sweeps all bn with bm fastest.
// vt epilogue: per-wave LDS transpose -> coalesced 16B stores.
// (R18 lesson: nontemporal stores here bypass L2 write-combining and
// 2x the kernel -- plain stores are correct.)
__global__ __launch_bounds__(256) void gemm_qkv(const u16* __restrict__ xb,
                                                const u16* __restrict__ waT,
                                                const float* __restrict__ bias,
                                                u16* __restrict__ q, u16* __restrict__ kk,
                                                u16* __restrict__ vt) {
  __shared__ u16 ldsU[2][128 * 64];
  u16* lA = ldsU[0];
  u16* lB = ldsU[1];
  int tid = threadIdx.x, lane = tid & 63, w = tid >> 6;
  int wr = w >> 1, wc = w & 1;
  int orig = blockIdx.x + gridDim.x * blockIdx.y;
  int xcd = orig & 7, local = orig >> 3;      // 1536 blocks: 8 XCDs x 192
  int bm = xcd * 8 + (local & 7);             // bm-chunk per XCD
  int bn = local >> 3;                        // 0..23, swept slowly
  f32x4 acc[4][4] = {};
  const u16* gA = xb + (size_t)bm * 128 * 1024;
  const u16* gB = waT + (size_t)bn * 128 * 1024;
  for (int k0 = 0; k0 < 1024; k0 += 64) {
    stage128(gA + k0, 1024, lA, tid);
    stage128(gB + k0, 1024, lB, tid);
    __syncthreads();
#pragma unroll
    for (int s = 0; s < 2; ++s) {
      bf16x8 af[4], bfr[4];
#pragma unroll
      for (int mi = 0; mi < 4; ++mi)
        af[mi] = frag_read(lA, wr * 64 + mi * 16 + (lane & 15), (lane >> 4) + s * 4);
#pragma unroll
      for (int ni = 0; ni < 4; ++ni)
        bfr[ni] = frag_read(lB, wc * 64 + ni * 16 + (lane & 15), (lane >> 4) + s * 4);
#pragma unroll
      for (int mi = 0; mi < 4; ++mi)
#pragma unroll
        for (int ni = 0; ni < 4; ++ni)
          acc[mi][ni] = MFMA16(af[mi], bfr[ni], acc[mi][ni]);
    }
    __syncthreads();
  }
  int m0 = bm * 128 + wr * 64;
  int n0 = bn * 128 + wc * 64;
  if (bn >= 16) {
    // ---- V^T part: transpose in per-wave LDS, store coalesced 16B ----
    int ln = lane & 15, g = lane >> 4;
    int hB = (n0 - 2048) >> 6;          // head, uniform per wave
    u16* scr = ldsU[0] + w * 4096;      // 8KB per wave
#pragma unroll
    for (int ni = 0; ni < 4; ++ni) {
      int d = ni * 16 + ln;
      float bv = bias[n0 + ni * 16 + ln];
#pragma unroll
      for (int mi = 0; mi < 4; ++mi) {
        u16x4 v4;
#pragma unroll
        for (int j = 0; j < 4; ++j) v4[j] = f2b(acc[mi][ni][j] + bv);
        int c = (mi * 4 + g) ^ (d & 15);  // chunk swizzle
        *reinterpret_cast<u16x4*>(reinterpret_cast<char*>(scr) + d * 128 + c * 8) = v4;
      }
    }
    asm volatile("s_waitcnt lgkmcnt(0)" ::: "memory");
    __builtin_amdgcn_sched_barrier(0);
    __builtin_amdgcn_wave_barrier();
    int bb = bm >> 4;
    int t0 = (bm & 15) * 128 + wr * 64 + (lane & 7) * 8;
#pragma unroll
    for (int p = 0; p < 8; ++p) {
      int dr = p * 8 + (lane >> 3);
      int c0 = (lane & 7) * 2;
      u16x4 lo = *reinterpret_cast<const u16x4*>(
          reinterpret_cast<const char*>(scr) + dr * 128 + ((c0 ^ (dr & 15)) * 8));
      u16x4 hi = *reinterpret_cast<const u16x4*>(
          reinterpret_cast<const char*>(scr) + dr * 128 + (((c0 + 1) ^ (dr & 15)) * 8));
      u16x8 o8;
      o8[0] = lo[0]; o8[1] = lo[1]; o8[2] = lo[2]; o8[3] = lo[3];
      o8[4] = hi[0]; o8[5] = hi[1]; o8[6] = hi[2]; o8[7] = hi[3];
      *reinterpret_cast<u16x8*>(vt + ((size_t)(bb * 16 + hB) * 64 + dr) * 2048 + t0) = o8;
    }
  } else {
    // ---- q/k parts: 16-lane-contiguous u16 stores (32B groups) ----
#pragma unroll
    for (int ni = 0; ni < 4; ++ni) {
      int col = n0 + ni * 16 + (lane & 15);
      float bv = bias[col];
      int part = col >> 10;
      int cin = col & 1023;
      int h = cin >> 6, d = cin & 63;
      float fct = (part == 0) ? QSCL : 1.0f;
#pragma unroll
      for (int mi = 0; mi < 4; ++mi) {
#pragma unroll
        for (int j = 0; j < 4; ++j) {
          int row = m0 + mi * 16 + (lane >> 4) * 4 + j;
          int b = row >> 11, t = row & 2047;
          u16 hv = f2b((acc[mi][ni][j] + bv) * fct);
          if (part == 0)
            q[(((size_t)(b * 16 + h) * 2048 + t) << 6) + d] = hv;
          else
            kk[(((size_t)(b * 16 + h) * 2048 + t) << 6) + d] = hv;
        }
      }
    }
  }
}

// ---------- GEMM2: out = att @ w_proj + b_proj (f32 out) ----------
// Same L2-blocked XCD mapping: bm-chunk per XCD, bn swept slowly.
__global__ __launch_bounds__(256) void gemm_proj(const u16* __restrict__ att,
                                                 const u16* __restrict__ wpT,
                                                 const float* __restrict__ bias,
                                                 float* __restrict__ out) {
  __shared__ u16 lA[128 * 64];
  __shared__ u16 lB[128 * 64];
  int tid = threadIdx.x, lane = tid & 63, w = tid >> 6;
  int wr = w >> 1, wc = w & 1;
  int orig = blockIdx.x + gridDim.x * blockIdx.y;
  int xcd = orig & 7, local = orig >> 3;      // 512 blocks: 8 XCDs x 64
  int bm = xcd * 8 + (local & 7);             // bm-chunk per XCD
  int bn = local >> 3;                        // 0..7
  f32x4 acc[4][4] = {};
  const u16* gA = att + (size_t)bm * 128 * 1024;
  const u16* gB = wpT + (size_t)bn * 128 * 1024;
  for (int k0 = 0; k0 < 1024; k0 += 64) {
    stage128(gA + k0, 1024, lA, tid);
    stage128(gB + k0, 1024, lB, tid);
    __syncthreads();
#pragma unroll
    for (int s = 0; s < 2; ++s) {
      bf16x8 af[4], bfr[4];
#pragma unroll
      for (int mi = 0; mi < 4; ++mi)
        af[mi] = frag_read(lA, wr * 64 + mi * 16 + (lane & 15), (lane >> 4) + s * 4);
#pragma unroll
      for (int ni = 0; ni < 4; ++ni)
        bfr[ni] = frag_read(lB, wc * 64 + ni * 16 + (lane & 15), (lane >> 4) + s * 4);
#pragma unroll
      for (int mi = 0; mi < 4; ++mi)
#pragma unroll
        for (int ni = 0; ni < 4; ++ni)
          acc[mi][ni] = MFMA16(af[mi], bfr[ni], acc[mi][ni]);
    }
    __syncthreads();
  }
  int m0 = bm * 128 + wr * 64;
  int n0 = bn * 128 + wc * 64;
#pragma unroll
  for (int ni = 0; ni < 4; ++ni) {
    int col = n0 + ni * 16 + (lane & 15);
    float bv = bias[col];
#pragma unroll
    for (int mi = 0; mi < 4; ++mi)
#pragma unroll
      for (int j = 0; j < 4; ++j) {
        int row = m0 + mi * 16 + (lane >> 4) * 4 + j;
        out[(size_t)row * 1024 + col] = acc[mi][ni][j] + bv;
      }
  }
}

// ---------- flash attention (proven 87.0us) ----------
// Swapped-operand S^T = mfma(K,Q), in-register P redistribution, K+V
// triple-buffered counted-vmcnt(4) pipeline. Zero-tail load balance:
//   g=0..9 : (31-g, 11+g); g=10: (21,10),(9,0); g=11: (8,1),(7,2),(6,3),(5,4)
// Grid 64x12 = 768 blocks = exactly 3/CU -> all co-resident, no tail round.
// (R11-R13: 1-deep S-pipelining spills to scratch here -- axis closed.)

__device__ __forceinline__ void stage_kv(const u16* kb, const u16* vb, int kt,
                                         u16* lK, u16* lV, int tid) {
  int lane = tid & 63, w = tid >> 6;
#pragma unroll
  for (int i = 0; i < 2; ++i) {
    int r = w * 16 + i * 8 + (lane >> 3);
    int cs = (lane & 7) ^ (r & 7);
    gload_lds16(kb + (size_t)(kt * 64 + r) * 64 + cs * 8, lK + r * 64 + (lane & 7) * 8);
    gload_lds16(vb + (size_t)r * 2048 + kt * 64 + cs * 8, lV + r * 64 + (lane & 7) * 8);
  }
}

// Redistribute two kc-pairs of packed P dwords into one B-fragment.
__device__ __forceinline__ bf16x8 pdist(u32 a0, u32 a1, u32 b0, u32 b1, bool odd) {
  intx2 r0 = __builtin_amdgcn_permlane32_swap((int)a0, (int)b0, false, false);
  intx2 r1 = __builtin_amdgcn_permlane32_swap((int)a1, (int)b1, false, false);
  u32 x0 = __shfl_xor((u32)r0[1], 16, 64);
  u32 x1 = __shfl_xor((u32)r1[1], 16, 64);
  u32 y0 = __shfl_xor((u32)r0[0], 16, 64);
  u32 y1 = __shfl_xor((u32)r1[0], 16, 64);
  u32x4 f;
  f[0] = odd ? x0 : (u32)r0[0];
  f[1] = odd ? x1 : (u32)r1[0];
  f[2] = odd ? (u32)r0[1] : y0;
  f[3] = odd ? (u32)r1[1] : y1;
  return __builtin_bit_cast(bf16x8, f);
}

__global__ __launch_bounds__(256, 3) void attn_fwd(const u16* __restrict__ q,
                                                   const u16* __restrict__ kk,
                                                   const u16* __restrict__ vt,
                                                   u16* __restrict__ att) {
  __shared__ u16 lK[3][64 * 64];
  __shared__ u16 lV[3][64 * 64];
  int tid = threadIdx.x, lane = tid & 63, w = tid >> 6;
  int ln = lane & 15, g = lane >> 4;
  int gh = g >> 1, gl = g & 1;
  bool godd = (g & 1) != 0;
  int bh = blockIdx.x;
  int grp = blockIdx.y;   // 0..11
  const u16* qb = q + (size_t)bh * 2048 * 64;
  const u16* kb = kk + (size_t)bh * 2048 * 64;
  const u16* vb = vt + (size_t)bh * 64 * 2048;
  int b = bh >> 4, h = bh & 15;

  // softmax for one state; emits the two P^T B-fragments in registers
  auto softmax_state = [&](f32x4* sf, float& m_r, float& l_r, f32x4* o,
                           bool domask, int k0, int qg,
                           bf16x8& pf0, bf16x8& pf1) {
    if (domask) {
#pragma unroll
      for (int kc = 0; kc < 4; ++kc)
#pragma unroll
        for (int j = 0; j < 4; ++j)
          if (k0 + kc * 16 + g * 4 + j > qg) sf[kc][j] = -1e30f;
    }
    f32x4 m4;
#pragma unroll
    for (int j = 0; j < 4; ++j)
      m4[j] = fmaxf(fmaxf(sf[0][j], sf[1][j]), fmaxf(sf[2][j], sf[3][j]));
    float mxl = fmaxf(fmaxf(m4[0], m4[1]), fmaxf(m4[2], m4[3]));
    if (!__all(mxl - m_r <= 8.f)) {  // defer-max: rescale only on big growth
      float mx = fmaxf(mxl, __shfl_xor(mxl, 16, 64));
      mx = fmaxf(mx, __shfl_xor(mx, 32, 64));
      mx = fmaxf(m_r, mx);
      float sc = __builtin_amdgcn_exp2f(m_r - mx);
      m_r = mx;
      l_r *= sc;
#pragma unroll
      for (int dc = 0; dc < 4; ++dc) o[dc] *= sc;
    }
    u32 d0[4], d1[4];
    float rsk[4];
#pragma unroll
    for (int kc = 0; kc < 4; ++kc) {
      u16x4 v4;
      float p0 = __builtin_amdgcn_exp2f(sf[kc][0] - m_r);
      float p1 = __builtin_amdgcn_exp2f(sf[kc][1] - m_r);
      float p2 = __builtin_amdgcn_exp2f(sf[kc][2] - m_r);
      float p3 = __builtin_amdgcn_exp2f(sf[kc][3] - m_r);
      v4[0] = f2b(p0); v4[1] = f2b(p1); v4[2] = f2b(p2); v4[3] = f2b(p3);
      rsk[kc] = (p0 + p1) + (p2 + p3);  // tree sum (iteration-local, no spill)
      u32x2 dd = __builtin_bit_cast(u32x2, v4);
      d0[kc] = dd[0];
      d1[kc] = dd[1];
    }
    l_r += (rsk[0] + rsk[1]) + (rsk[2] + rsk[3]);
    pf0 = pdist(d0[0], d1[0], d0[1], d1[1], godd);
    pf1 = pdist(d0[2], d1[2], d0[3], d1[3], godd);
  };

  // O^T -> O transpose via per-wave lK[0] scratch, coalesced 16B stores
  u16* lPw = &lK[0][0] + w * 1024;
  int prow = ln * 128;
  int xorq = (ln & 7) << 4;
  auto epi = [&](const f32x4* o, float l_r, int q0w) {
    float lt = l_r + __shfl_xor(l_r, 16, 64);
    lt += __shfl_xor(lt, 32, 64);
    float inv = __builtin_amdgcn_rcpf(lt);
#pragma unroll
    for (int dc = 0; dc < 4; ++dc) {
      u16x4 v4;
#pragma unroll
      for (int j = 0; j < 4; ++j) v4[j] = f2b(o[dc][j] * inv);
      *reinterpret_cast<u16x4*>(reinterpret_cast<char*>(lPw) + prow +
                                ((((dc << 1) + gh) << 4) ^ xorq) + gl * 8) = v4;
    }
    asm volatile("s_waitcnt lgkmcnt(0)" ::: "memory");
    __builtin_amdgcn_sched_barrier(0);
    __builtin_amdgcn_wave_barrier();
    bf16x8 r0 = frag_read(lPw, ln, g);
    bf16x8 r1 = frag_read(lPw, ln, g + 4);
    __builtin_amdgcn_sched_barrier(0);
    int t = q0w + ln;
    u16* dst = att + (size_t)(b * 2048 + t) * 1024 + h * 64;
    *reinterpret_cast<bf16x8*>(dst + g * 8) = r0;
    *reinterpret_cast<bf16x8*>(dst + 32 + g * 8) = r1;
  };

  int njobs = (grp < 10) ? 1 : ((grp == 10) ? 2 : 4);

  for (int jj = 0; jj < njobs; ++jj) {
    int qtB, qtA;  // uniform scalars per job
    if (grp < 10) {
      qtB = 31 - grp; qtA = 11 + grp;
    } else if (grp == 10) {
      qtB = jj ? 9 : 21; qtA = jj ? 0 : 10;
    } else {
      qtB = 8 - jj; qtA = 1 + jj;
    }
    int q0A = qtA * 64 + w * 16;
    int q0B = qtB * 64 + w * 16;

    bf16x8 aqA[2], aqB[2];
    {
      const u16* pa = qb + (size_t)(q0A + ln) * 64 + g * 8;
      const u16* pb = qb + (size_t)(q0B + ln) * 64 + g * 8;
      aqA[0] = *reinterpret_cast<const bf16x8*>(pa);
      aqA[1] = *reinterpret_cast<const bf16x8*>(pa + 32);
      aqB[0] = *reinterpret_cast<const bf16x8*>(pb);
      aqB[1] = *reinterpret_cast<const bf16x8*>(pb + 32);
    }

    float mA = -1e30f, lAx = 0.f, mB = -1e30f, lBx = 0.f;
    f32x4 oA[4] = {}, oB[4] = {};

    // prologue: two tiles in flight before the loop (qtB >= 1 for all jobs)
    stage_kv(kb, vb, 0, &lK[0][0], &lV[0][0], tid);
    if (qtB >= 1) stage_kv(kb, vb, 1, &lK[1][0], &lV[1][0], tid);

    for (int kt = 0; kt <= qtB; ++kt) {
      // wait for tile kt (leave tile kt+1's 4 loads in flight), then sync
      if (kt < qtB) {
        asm volatile("s_waitcnt vmcnt(4)" ::: "memory");
      } else {
        asm volatile("s_waitcnt vmcnt(0)" ::: "memory");
      }
      __builtin_amdgcn_s_barrier();
      // prefetch tile kt+2 into the buffer last read at compute(kt-1)
      if (kt + 2 <= qtB)
        stage_kv(kb, vb, kt + 2, &lK[(kt + 2) % 3][0], &lV[(kt + 2) % 3][0], tid);
      int cur = kt % 3;
      const u16* Kt = &lK[cur][0];
      const u16* Vt = &lV[cur][0];
      bool doA = (kt <= qtA);

      // QK^T both states, K-fragments shared
      f32x4 sB[4], sA[4];
      __builtin_amdgcn_s_setprio(1);
#pragma unroll
      for (int kc = 0; kc < 4; ++kc) {
        f32x4 zB = {}, zA = {};
#pragma unroll
        for (int s = 0; s < 2; ++s) {
          bf16x8 kf = frag_read(Kt, kc * 16 + ln, g + 4 * s);
          zB = MFMA16(kf, aqB[s], zB);
          if (doA) zA = MFMA16(kf, aqA[s], zA);
        }
        sB[kc] = zB;
        sA[kc] = zA;
      }
      __builtin_amdgcn_s_setprio(0);

      // V-fragment register cache (shared by both states; loads overlap SM_B)
      bf16x8 vf0[4], vf1[4];
#pragma unroll
      for (int dc = 0; dc < 4; ++dc) {
        vf0[dc] = frag_read(Vt, dc * 16 + ln, g);
        vf1[dc] = frag_read(Vt, dc * 16 + ln, g + 4);
      }

      bf16x8 pB0, pB1, pA0, pA1;
      softmax_state(sB, mB, lBx, oB, kt == qtB, kt * 64, q0B + ln, pB0, pB1);
      __builtin_amdgcn_s_setprio(1);
#pragma unroll
      for (int dc = 0; dc < 4; ++dc) {
        oB[dc] = MFMA16(vf0[dc], pB0, oB[dc]);
        oB[dc] = MFMA16(vf1[dc], pB1, oB[dc]);
      }
      __builtin_amdgcn_s_setprio(0);
      if (doA) {
        // SM_A's VALU chain overlaps PV_B's MFMAs (independent)
        softmax_state(sA, mA, lAx, oA, kt == qtA, kt * 64, q0A + ln, pA0, pA1);
        __builtin_amdgcn_s_setprio(1);
#pragma unroll
        for (int dc = 0; dc < 4; ++dc) {
          oA[dc] = MFMA16(vf0[dc], pA0, oA[dc]);
          oA[dc] = MFMA16(vf1[dc], pA1, oA[dc]);
        }
        __builtin_amdgcn_s_setprio(0);
      }
    }

    // epilogue: reduce l; transpose O^T -> O via lK[0] scratch
    __syncthreads();  // everyone done with K/V LDS for this job
    epi(oB, lBx, q0B);
    epi(oA, lAx, q0A);
    __syncthreads();  // scratch reads done before next job's staging
  }
}

extern "C" void kernel_launch(void* const* d_in, const int* in_sizes, int n_in,
                              void* d_out, int out_size, void* d_ws, size_t ws_size,
                              hipStream_t stream) {
  const float* x = (const float*)d_in[0];
  const float* w_attn = (const float*)d_in[1];
  const float* b_attn = (const float*)d_in[2];
  const float* w_proj = (const float*)d_in[3];
  const float* b_proj = (const float*)d_in[4];
  float* out = (float*)d_out;

  // workspace (u16 units): xb 8.39M (aliased by att after gemm_qkv),
  // waT 3.15M, wpT 1.05M, vt 8.39M  => ~42 MB total
  u16* ws = (u16*)d_ws;
  u16* xb = ws;
  u16* waT = xb + 8388608;
  u16* wpT = waT + 3145728;
  u16* vtx = wpT + 1048576;
  u16* att = xb;  // alias: xb dead after gemm_qkv
  // q/k live in d_out (33.5MB) as scratch; overwritten by gemm_proj at the end
  u16* qx = (u16*)d_out;
  u16* kx = qx + 8388608;

  cvt_f32_bf16<<<8192, 256, 0, stream>>>(x, xb, 2097152);
  transpose_cvt2<<<dim3(96, 32, 2), 256, 0, stream>>>(w_attn, waT, w_proj, wpT);
  gemm_qkv<<<dim3(64, 24), 256, 0, stream>>>(xb, waT, b_attn, qx, kx, vtx);
  attn_fwd<<<dim3(64, 12), 256, 0, stream>>>(qx, kx, vtx, att);
  gemm_proj<<<dim3(64, 8), 256, 0, stream>>>(att, wpT, b_proj, out);
}